// Round 7
// baseline (144.611 us; speedup 1.0000x reference)
//
#include <hip/hip_runtime.h>

#define WAVE 64

typedef float v4f __attribute__((ext_vector_type(4)));

// ---------------------------------------------------------------------------
// Single fused kernel: one wave per segment, bounds found in-kernel.
//
// lower_bound search, wave-parallel: lanes 0-31 resolve lower_bound(wid),
// lanes 32-63 resolve lower_bound(wid+1), simultaneously. Seeded by the
// statistical prior g = t*N/B (batch = sorted uniform randint => seg_start[t]
// ~ Binomial(N, t/B), sigma <= sqrt(N)/2 ~ 1118). Window +-8192 = 7.3 sigma;
// two validation loads fall back to [0,N] if the prior misses (correct for
// ANY sorted input, merely slower). Then 32-ary probe rounds: 32 lanes probe
// stride-s positions, ballot locates the bracket, range shrinks 32x/round:
// 16K window -> 512 -> 16 -> 1 (~3 rounds, each one L2-resident load).
// ~1300 dep-chain cycles/wave vs R1's serial binary search ~5700 (which
// regressed +4.8us); eliminates kernel A (~5us) + one dispatch gap.
//
// Accumulation body = R3's proven 4-deep NT structure (141.0us best).
// ---------------------------------------------------------------------------
__global__ void __launch_bounds__(256)
fused_seg_mean_mlp(const v4f* __restrict__ x,
                   const int* __restrict__ batch,
                   const float* __restrict__ u,
                   const float* __restrict__ W1,   // [5,5] row-major
                   const float* __restrict__ b1,   // [5]
                   const float* __restrict__ W2,   // [5]
                   const float* __restrict__ b2,   // [1]
                   float* __restrict__ out,
                   int N, int B) {
    const int wid  = (blockIdx.x * blockDim.x + threadIdx.x) >> 6;
    const int lane = threadIdx.x & (WAVE - 1);
    if (wid >= B) return;

    // ---- dual lower_bound via lane-group 32-ary search ----
    const int t   = wid + (lane >> 5);      // group 0: wid, group 1: wid+1
    const int sub = lane & 31;

    const long long g = ((long long)t * (long long)N) / (long long)B;
    int lo = (int)(g - 8192 > 0 ? g - 8192 : 0);
    int hi = (int)(g + 8192 < (long long)N ? g + 8192 : (long long)N);

    // Validate the prior window (2 broadcast loads per group); fallback [0,N].
    if (lo > 0 && batch[lo - 1] >= t) lo = 0;
    if (hi < N && batch[hi] < t)      hi = N;

    // Invariant: lower_bound(t) in [lo, hi].
    while (lo < hi) {
        const int range = hi - lo;
        const int s = (range + 31) >> 5;                 // >= 1
        const long long pi = (long long)lo + (long long)sub * (long long)s;
        bool ge = true;                                   // padded probes
        if (pi < (long long)hi) ge = (batch[pi] >= t);
        const unsigned long long bal = __ballot(ge);
        const unsigned grp = (lane >= 32) ? (unsigned)(bal >> 32)
                                          : (unsigned)(bal & 0xffffffffu);
        if (grp == 0u) {
            // all real probes < t: bound in (lo+31s, hi]
            const int nlo = lo + 31 * s + 1;
            lo = (nlo < hi) ? nlo : hi;
        } else {
            const int f = __builtin_ctz(grp);
            if (f == 0) {
                hi = lo;                                  // batch[lo] >= t
            } else {
                const int nhi = lo + f * s;
                hi = (nhi < hi) ? nhi : hi;
                lo = lo + (f - 1) * s + 1;
            }
        }
    }
    // Both groups converged; lo == lower_bound(t) uniformly per group.
    const int start = __shfl(lo, 0);
    const int end   = __shfl(lo, 32);

    // ---- R3 accumulation: 4-deep NT float4 loads ----
    v4f a0 = (v4f)(0.f);
    v4f a1 = (v4f)(0.f);
    v4f a2 = (v4f)(0.f);
    v4f a3 = (v4f)(0.f);

    int i = start + lane;
    for (; i + 3 * WAVE < end; i += 4 * WAVE) {
        v4f v0 = __builtin_nontemporal_load(&x[i]);
        v4f v1 = __builtin_nontemporal_load(&x[i + WAVE]);
        v4f v2 = __builtin_nontemporal_load(&x[i + 2 * WAVE]);
        v4f v3 = __builtin_nontemporal_load(&x[i + 3 * WAVE]);
        a0 += v0; a1 += v1; a2 += v2; a3 += v3;
    }
    for (; i < end; i += WAVE) {
        a0 += __builtin_nontemporal_load(&x[i]);
    }

    a0 += a1; a2 += a3; a0 += a2;

    float sx = a0.x, sy = a0.y, sz = a0.z, sw = a0.w;
    #pragma unroll
    for (int off = 32; off > 0; off >>= 1) {
        sx += __shfl_down(sx, off);
        sy += __shfl_down(sy, off);
        sz += __shfl_down(sz, off);
        sw += __shfl_down(sw, off);
    }

    if (lane == 0) {
        const int cnt = end - start;
        const float inv = (cnt > 0) ? (1.0f / (float)cnt) : 0.0f;

        float h[5];
        h[0] = u[wid];
        h[1] = sx * inv;
        h[2] = sy * inv;
        h[3] = sz * inv;
        h[4] = sw * inv;

        float o = b2[0];
        #pragma unroll
        for (int j = 0; j < 5; ++j) {
            float s2 = b1[j];
            #pragma unroll
            for (int i2 = 0; i2 < 5; ++i2) s2 += h[i2] * W1[i2 * 5 + j];
            s2 = (s2 > 0.0f) ? s2 : 0.1f * s2;   // leaky_relu, slope 0.1
            o += s2 * W2[j];
        }
        out[wid] = o;
    }
}

extern "C" void kernel_launch(void* const* d_in, const int* in_sizes, int n_in,
                              void* d_out, int out_size, void* d_ws, size_t ws_size,
                              hipStream_t stream) {
    const float* x     = (const float*)d_in[0];  // [N,4]
    const int*   batch = (const int*)  d_in[1];  // [N]
    const float* u     = (const float*)d_in[2];  // [B,1]
    const float* W1    = (const float*)d_in[3];  // [5,5]
    const float* b1    = (const float*)d_in[4];  // [5]
    const float* W2    = (const float*)d_in[5];  // [5,1]
    const float* b2    = (const float*)d_in[6];  // [1]
    float* out = (float*)d_out;

    const int N = in_sizes[0] / 4;
    const int B = out_size;                      // output is [B,1]

    (void)d_ws; (void)ws_size;                   // workspace unused

    const int threads = 256;
    const int blocks  = (int)(((long long)B * WAVE + threads - 1) / threads);
    fused_seg_mean_mlp<<<blocks, threads, 0, stream>>>(
        (const v4f*)x, batch, u, W1, b1, W2, b2, out, N, B);
}

// Round 8
// 140.424 us; speedup vs baseline: 1.0298x; 1.0298x over previous
//
#include <hip/hip_runtime.h>

#define WAVE 64

// clang vector types: __builtin_nontemporal_load requires a pointer to
// integer/float/pointer or a VECTOR of such (HIP_vector_type classes are
// rejected).
typedef float v4f __attribute__((ext_vector_type(4)));
typedef int   v4i __attribute__((ext_vector_type(4)));

// ---------------------------------------------------------------------------
// Kernel A: segment start offsets from the sorted batch index, vectorized.
// seg_start[s] = min{ i : batch[i] >= s } for s in [0,B]; seg_start[B] = N.
// One int4 per thread; the quad's predecessor element comes from the
// neighbor lane via __shfl_up (only lane 0 of each wave loads it).
// Every s in [0,B] is written exactly once -> no init needed (poison-immune).
// Session evidence: bandwidth-optimal 20 MB sequential pass beats in-kernel
// search fusion (R1 serial: +8.3us, R7 32-ary+prior: +3.6us vs this).
// ---------------------------------------------------------------------------
__global__ void find_starts4_kernel(const int* __restrict__ batch,
                                    int* __restrict__ seg_start,
                                    int N, int B) {
    const int tid  = blockIdx.x * blockDim.x + threadIdx.x;
    const int lane = threadIdx.x & (WAVE - 1);
    const long long i0 = (long long)tid * 4;
    const bool in   = (i0 < N);
    const bool full = (i0 + 3 < N);

    v4i q = (v4i)(0);
    if (full) q = __builtin_nontemporal_load(&((const v4i*)batch)[tid]);

    // Predecessor of this quad = last element of the previous thread's quad.
    // All threads participate in the shuffle before any early exit.
    int prevw = __shfl_up(q.w, 1);

    if (!in) return;

    int prev;
    if (lane == 0) prev = (i0 == 0) ? -1 : batch[i0 - 1];
    else           prev = prevw;      // predecessor quad is always full here

    if (full) {
        int e[4] = {q.x, q.y, q.z, q.w};
        #pragma unroll
        for (int k = 0; k < 4; ++k) {
            int cur = e[k];
            for (int s = prev + 1; s <= cur; ++s) seg_start[s] = (int)(i0 + k);
            prev = cur;
        }
    } else {
        for (long long j = i0; j < N; ++j) {
            int cur = batch[j];
            for (int s = prev + 1; s <= cur; ++s) seg_start[s] = (int)j;
            prev = cur;
        }
    }

    if (i0 + 4 >= N) {  // owner of the final quad writes the tail sentinels
        for (int s = prev + 1; s <= B; ++s) seg_start[s] = N;
    }
}

// ---------------------------------------------------------------------------
// Kernel B: one wave per segment. Coalesced float4 accumulation, 4x unrolled
// (4 non-temporal loads in flight), wave tree-reduction, then lane 0 computes
// the fused MLP: h=[u,mean] -> leaky_relu(h@W1+b1) -> @W2+b2.
// Session evidence: this loop structure measured best (141.0us); 8-slot
// exec-masked (R6) and plain/allocating loads (R5) were neutral-to-worse;
// node-centric segmented-scan+atomics (R4) was DS-throughput-bound, +23us.
// ---------------------------------------------------------------------------
__global__ void __launch_bounds__(256)
seg_mean_mlp_kernel(const v4f* __restrict__ x,
                    const int* __restrict__ seg_start,
                    const float* __restrict__ u,
                    const float* __restrict__ W1,   // [5,5] row-major
                    const float* __restrict__ b1,   // [5]
                    const float* __restrict__ W2,   // [5]
                    const float* __restrict__ b2,   // [1]
                    float* __restrict__ out, int B) {
    const int wid  = (blockIdx.x * blockDim.x + threadIdx.x) >> 6;
    const int lane = threadIdx.x & (WAVE - 1);
    if (wid >= B) return;

    const int start = seg_start[wid];
    const int end   = seg_start[wid + 1];

    v4f a0 = (v4f)(0.f);
    v4f a1 = (v4f)(0.f);
    v4f a2 = (v4f)(0.f);
    v4f a3 = (v4f)(0.f);

    int i = start + lane;
    for (; i + 3 * WAVE < end; i += 4 * WAVE) {
        v4f v0 = __builtin_nontemporal_load(&x[i]);
        v4f v1 = __builtin_nontemporal_load(&x[i + WAVE]);
        v4f v2 = __builtin_nontemporal_load(&x[i + 2 * WAVE]);
        v4f v3 = __builtin_nontemporal_load(&x[i + 3 * WAVE]);
        a0 += v0; a1 += v1; a2 += v2; a3 += v3;
    }
    for (; i < end; i += WAVE) {
        v4f v = __builtin_nontemporal_load(&x[i]);
        a0 += v;
    }

    a0 += a1; a2 += a3; a0 += a2;

    float sx = a0.x, sy = a0.y, sz = a0.z, sw = a0.w;
    #pragma unroll
    for (int off = 32; off > 0; off >>= 1) {
        sx += __shfl_down(sx, off);
        sy += __shfl_down(sy, off);
        sz += __shfl_down(sz, off);
        sw += __shfl_down(sw, off);
    }

    if (lane == 0) {
        const int cnt = end - start;
        const float inv = (cnt > 0) ? (1.0f / (float)cnt) : 0.0f;

        float h[5];
        h[0] = u[wid];
        h[1] = sx * inv;
        h[2] = sy * inv;
        h[3] = sz * inv;
        h[4] = sw * inv;

        float o = b2[0];
        #pragma unroll
        for (int j = 0; j < 5; ++j) {
            float s = b1[j];
            #pragma unroll
            for (int i2 = 0; i2 < 5; ++i2) s += h[i2] * W1[i2 * 5 + j];
            s = (s > 0.0f) ? s : 0.1f * s;   // leaky_relu, slope 0.1
            o += s * W2[j];
        }
        out[wid] = o;
    }
}

extern "C" void kernel_launch(void* const* d_in, const int* in_sizes, int n_in,
                              void* d_out, int out_size, void* d_ws, size_t ws_size,
                              hipStream_t stream) {
    const float* x     = (const float*)d_in[0];  // [N,4]
    const int*   batch = (const int*)  d_in[1];  // [N]
    const float* u     = (const float*)d_in[2];  // [B,1]
    const float* W1    = (const float*)d_in[3];  // [5,5]
    const float* b1    = (const float*)d_in[4];  // [5]
    const float* W2    = (const float*)d_in[5];  // [5,1]
    const float* b2    = (const float*)d_in[6];  // [1]
    float* out = (float*)d_out;

    const int N = in_sizes[0] / 4;
    const int B = out_size;                      // output is [B,1]

    int* seg_start = (int*)d_ws;                 // [B+1] ints, fully rewritten

    const int quads = (N + 3) / 4;
    find_starts4_kernel<<<(quads + 255) / 256, 256, 0, stream>>>(batch, seg_start, N, B);

    const int threads = 256;
    const int blocks  = (int)(((long long)B * WAVE + threads - 1) / threads);
    seg_mean_mlp_kernel<<<blocks, threads, 0, stream>>>(
        (const v4f*)x, seg_start, u, W1, b1, W2, b2, out, B);
}